// Round 12
// baseline (479.462 us; speedup 1.0000x reference)
//
#include <hip/hip_runtime.h>
#include <stdint.h>

// Problem sizes (fixed by the reference)
#define BSZ 4096
#define HDIM 1024
#define MMEM 4096
#define KOUT 8

typedef __attribute__((ext_vector_type(4))) float f32x4;
typedef __attribute__((ext_vector_type(8))) short s16x8;

__device__ __forceinline__ unsigned short f2bf(float f) {
    uint32_t u = __builtin_bit_cast(uint32_t, f);
    u += 0x7FFFu + ((u >> 16) & 1u);   // round-to-nearest-even
    return (unsigned short)(u >> 16);
}

// ------------- f32 -> bf16 convert, two sources (grid.y selects) -------------
__global__ __launch_bounds__(256) void cvt2_f32_bf16(
    const float* __restrict__ in0, const float* __restrict__ in1,
    unsigned short* __restrict__ out, int n4) {
    int i = blockIdx.x * blockDim.x + threadIdx.x;
    if (i >= n4) return;
    const float* src = blockIdx.y ? in1 : in0;
    float4 v = reinterpret_cast<const float4*>(src)[i];
    ushort4 o;
    o.x = f2bf(v.x); o.y = f2bf(v.y); o.z = f2bf(v.z); o.w = f2bf(v.w);
    reinterpret_cast<ushort4*>(out + (size_t)blockIdx.y * n4 * 4)[i] = o;
}

// ------- memory [M,H] f32 -> mem_bf [M,H] bf16 + memT [H,M] bf16 -------
__global__ __launch_bounds__(256) void transpose_cvt(
    const float* __restrict__ mem, unsigned short* __restrict__ mem_bf,
    unsigned short* __restrict__ memT, int M, int H) {
    __shared__ float tile[32][33];
    const int h0 = blockIdx.x * 32, m0 = blockIdx.y * 32;
    const int tx = threadIdx.x, ty = threadIdx.y;
#pragma unroll
    for (int j = 0; j < 4; ++j) {
        int m = m0 + ty + j * 8;
        float v = mem[(size_t)m * H + h0 + tx];
        tile[ty + j * 8][tx] = v;
        mem_bf[(size_t)m * H + h0 + tx] = f2bf(v);
    }
    __syncthreads();
#pragma unroll
    for (int j = 0; j < 4; ++j) {
        int h = h0 + ty + j * 8;
        memT[(size_t)h * M + m0 + tx] = f2bf(tile[tx][ty + j * 8]);
    }
}

// ---------------- NT bf16 GEMM: C[M,N] = A[M,K] * B[N,K]^T ----------------
// 128x128 tile, BK=32, 4 waves (2x2), 16x16x32 MFMA, fragment-ordered LDS,
// global_load_lds width 16, XCD-bijective block swizzle (requires nwg%8==0).
// grid.z = nab * KSPLIT: ab = z % nab selects input set (zA/zB/zC offsets),
// ks = z / nab selects the K-chunk (split-K for occupancy/TLP; round-8
// profile: 1 block/CU -> latency-bound at 558 GB/s, Occupancy 10.9%).
// EPI: 1 = split-K atomicAdd + bias[col] (bias only from ks==0 blocks)
//      3 = e = exp(acc), store bf16 to Ebf, atomicAdd row sums to rowsum
//      5 = split-K atomicAdd partial (wm; /rowsum deferred to hub_expand)
template <int EPI>
__global__ __launch_bounds__(256, 2) void gemm_bt(
    const unsigned short* __restrict__ A, const unsigned short* __restrict__ Bm,
    float* __restrict__ C, unsigned short* __restrict__ Ebf,
    int N, int Kdim, int nab,
    const float* __restrict__ bias, const float* __restrict__ bias1,
    size_t zA, size_t zB, size_t zC, float* __restrict__ rowsum) {
    __shared__ alignas(16) unsigned short ldsA[4096];  // 8 KB: [g:8][c:4][r:16][8 bf16]
    __shared__ alignas(16) unsigned short ldsB[4096];

    const int tid  = threadIdx.x;
    const int lane = tid & 63;
    const int w    = tid >> 6;
    const int wm   = w >> 1, wn = w & 1;

    // grid.z decode: input set + K-chunk
    const int z  = blockIdx.z;
    const int ab = z % nab;
    const int ks = z / nab;
    const int KSPLIT = gridDim.z / nab;
    const int Kc = Kdim / KSPLIT;            // this block's K extent
    A  += (size_t)ab * zA + (size_t)ks * Kc;
    Bm += (size_t)ab * zB + (size_t)ks * Kc;
    C  += (size_t)ab * zC;
    const float* bi = (ab != 0 && bias1 != nullptr) ? bias1 : bias;

    // XCD-bijective swizzle: consecutive swizzled ids (same A-panel, all
    // B-panels) land on one XCD -> A fetched by exactly one XCD L2.
    const int gx  = gridDim.x;
    const int nwg = gx * gridDim.y;          // all launches: nwg % 8 == 0
    const int lid = blockIdx.y * gx + blockIdx.x;
    const int s   = (lid & 7) * (nwg >> 3) + (lid >> 3);
    const int m0 = (s / gx) * 128, n0 = (s % gx) * 128;

    // staging decomposition: chunk ci = i*256 + tid ; g=ci>>6, c=(ci>>4)&3, r=ci&15
    const int g0 = tid >> 6;
    const int ck = (tid >> 4) & 3;
    const int rr = tid & 15;
    size_t baseA0 = (size_t)(m0 + g0 * 16 + rr) * Kdim + ck * 8;
    size_t baseA1 = baseA0 + (size_t)64 * Kdim;
    size_t baseB0 = (size_t)(n0 + g0 * 16 + rr) * Kdim + ck * 8;
    size_t baseB1 = baseB0 + (size_t)64 * Kdim;

    char* ldsAc = (char*)ldsA;
    char* ldsBc = (char*)ldsB;
    char* dA0 = ldsAc + tid * 16;
    char* dA1 = ldsAc + 4096 + tid * 16;
    char* dB0 = ldsBc + tid * 16;
    char* dB1 = ldsBc + 4096 + tid * 16;

    f32x4 acc[4][4] = {};

    const int frOff = ((lane >> 4) * 256 + (lane & 15) * 16);  // within 1KB group

    for (int ksi = 0; ksi < Kc; ksi += 32) {
        __builtin_amdgcn_global_load_lds(
            (const __attribute__((address_space(1))) void*)(A + baseA0 + ksi),
            (__attribute__((address_space(3))) void*)dA0, 16, 0, 0);
        __builtin_amdgcn_global_load_lds(
            (const __attribute__((address_space(1))) void*)(A + baseA1 + ksi),
            (__attribute__((address_space(3))) void*)dA1, 16, 0, 0);
        __builtin_amdgcn_global_load_lds(
            (const __attribute__((address_space(1))) void*)(Bm + baseB0 + ksi),
            (__attribute__((address_space(3))) void*)dB0, 16, 0, 0);
        __builtin_amdgcn_global_load_lds(
            (const __attribute__((address_space(1))) void*)(Bm + baseB1 + ksi),
            (__attribute__((address_space(3))) void*)dB1, 16, 0, 0);
        __syncthreads();   // drains vmcnt before barrier

        s16x8 af[4], bfv[4];
#pragma unroll
        for (int m = 0; m < 4; ++m)
            af[m] = *(const s16x8*)(ldsAc + (wm * 4 + m) * 1024 + frOff);
#pragma unroll
        for (int n = 0; n < 4; ++n)
            bfv[n] = *(const s16x8*)(ldsBc + (wn * 4 + n) * 1024 + frOff);
#pragma unroll
        for (int m = 0; m < 4; ++m)
#pragma unroll
            for (int n = 0; n < 4; ++n)
                acc[m][n] = __builtin_amdgcn_mfma_f32_16x16x32_bf16(
                    af[m], bfv[n], acc[m][n], 0, 0, 0);
        __syncthreads();
    }

    if (EPI == 1) {
        // split-K partial with bias contributed exactly once (ks==0)
#pragma unroll
        for (int m = 0; m < 4; ++m)
#pragma unroll
            for (int n = 0; n < 4; ++n) {
                int rowb = m0 + wm * 64 + m * 16 + (lane >> 4) * 4;
                int col  = n0 + wn * 64 + n * 16 + (lane & 15);
                float bv = (ks == 0) ? bi[col] : 0.f;
#pragma unroll
                for (int r = 0; r < 4; ++r)
                    atomicAdd(&C[(size_t)(rowb + r) * N + col], acc[m][n][r] + bv);
            }
    }

    if (EPI == 3) {
        // exp in place (logits bounded ~|30| << 88: no max subtraction needed)
#pragma unroll
        for (int m = 0; m < 4; ++m)
#pragma unroll
            for (int n = 0; n < 4; ++n)
#pragma unroll
                for (int r = 0; r < 4; ++r)
                    acc[m][n][r] = __expf(acc[m][n][r]);
        // store e as bf16
#pragma unroll
        for (int m = 0; m < 4; ++m)
#pragma unroll
            for (int n = 0; n < 4; ++n) {
                int rowb = m0 + wm * 64 + m * 16 + (lane >> 4) * 4;
                int col  = n0 + wn * 64 + n * 16 + (lane & 15);
#pragma unroll
                for (int r = 0; r < 4; ++r)
                    Ebf[(size_t)(rowb + r) * N + col] = f2bf(acc[m][n][r]);
            }
        // per-row partial sums (this wave covers 64 cols of the row):
        // sum over n-frags, butterfly over the 16-lane col group, one atomic.
#pragma unroll
        for (int m = 0; m < 4; ++m)
#pragma unroll
            for (int r = 0; r < 4; ++r) {
                float sv = (acc[m][0][r] + acc[m][1][r]) +
                           (acc[m][2][r] + acc[m][3][r]);
                sv += __shfl_xor(sv, 1);
                sv += __shfl_xor(sv, 2);
                sv += __shfl_xor(sv, 4);
                sv += __shfl_xor(sv, 8);
                if ((lane & 15) == 0) {
                    int row = m0 + wm * 64 + m * 16 + (lane >> 4) * 4 + r;
                    atomicAdd(&rowsum[row], sv);
                }
            }
    }

    if (EPI == 5) {
        // split-K partial accumulate (normalization deferred to hub_expand)
#pragma unroll
        for (int m = 0; m < 4; ++m)
#pragma unroll
            for (int n = 0; n < 4; ++n) {
                int rowb = m0 + wm * 64 + m * 16 + (lane >> 4) * 4;
                int col  = n0 + wn * 64 + n * 16 + (lane & 15);
#pragma unroll
                for (int r = 0; r < 4; ++r)
                    atomicAdd(&C[(size_t)(rowb + r) * N + col], acc[m][n][r]);
            }
    }
}

// -------- u = ta/max(||ta||,eps) + tb/max(||tb||,eps)  (bf16 out) --------
__global__ __launch_bounds__(256) void norm_add(
    const float* __restrict__ ta, const float* __restrict__ tb,
    unsigned short* __restrict__ u, int H) {
    const int row = blockIdx.x;
    const int tid = threadIdx.x;
    float4 va = reinterpret_cast<const float4*>(ta + (size_t)row * H)[tid];
    float4 vb = reinterpret_cast<const float4*>(tb + (size_t)row * H)[tid];
    float sa = va.x * va.x + va.y * va.y + va.z * va.z + va.w * va.w;
    float sb = vb.x * vb.x + vb.y * vb.y + vb.z * vb.z + vb.w * vb.w;
#pragma unroll
    for (int off = 32; off; off >>= 1) {
        sa += __shfl_xor(sa, off);
        sb += __shfl_xor(sb, off);
    }
    __shared__ float reda[4], redb[4];
    if ((tid & 63) == 0) { reda[tid >> 6] = sa; redb[tid >> 6] = sb; }
    __syncthreads();
    float SA = (reda[0] + reda[1]) + (reda[2] + reda[3]);
    float SB = (redb[0] + redb[1]) + (redb[2] + redb[3]);
    float ra = 1.f / fmaxf(sqrtf(SA), 1e-12f);
    float rb = 1.f / fmaxf(sqrtf(SB), 1e-12f);
    ushort4 o;
    o.x = f2bf(va.x * ra + vb.x * rb);
    o.y = f2bf(va.y * ra + vb.y * rb);
    o.z = f2bf(va.z * ra + vb.z * rb);
    o.w = f2bf(va.w * ra + vb.w * rb);
    reinterpret_cast<ushort4*>(u + (size_t)row * H)[tid] = o;
}

// ---- out[b,k,h] = (wm_raw[b,h]/rowsum[b])*Wc[k] + bc[k]  (streaming) ----
__global__ __launch_bounds__(256) void hub_expand(
    const float* __restrict__ wm, const float* __restrict__ rowsum,
    const float* __restrict__ Wc, const float* __restrict__ bc,
    float* __restrict__ out) {
    const int b = blockIdx.x;
    const int t = threadIdx.x;           // 256 threads * float4 = 1024 cols
    float rs = 1.0f / rowsum[b];
    float4 v = reinterpret_cast<const float4*>(wm)[(size_t)b * 256 + t];
    v.x *= rs; v.y *= rs; v.z *= rs; v.w *= rs;
#pragma unroll
    for (int k = 0; k < KOUT; ++k) {
        float wv = Wc[k], bv = bc[k];
        float4 o;
        o.x = v.x * wv + bv; o.y = v.y * wv + bv;
        o.z = v.z * wv + bv; o.w = v.w * wv + bv;
        reinterpret_cast<float4*>(out)[((size_t)b * KOUT + k) * 256 + t] = o;
    }
}

extern "C" void kernel_launch(void* const* d_in, const int* in_sizes, int n_in,
                              void* d_out, int out_size, void* d_ws, size_t ws_size,
                              hipStream_t stream) {
    const float* a      = (const float*)d_in[0];
    const float* b      = (const float*)d_in[1];
    const float* memory = (const float*)d_in[2];
    const float* Wa     = (const float*)d_in[3];
    const float* ba     = (const float*)d_in[4];
    const float* Wb     = (const float*)d_in[5];
    const float* bb     = (const float*)d_in[6];
    const float* Wc     = (const float*)d_in[7];
    const float* bc     = (const float*)d_in[8];
    float* out = (float*)d_out;

    const int B = BSZ, H = HDIM, M = MMEM;
    char* ws = (char*)d_ws;
    const size_t MB = 1u << 20;
    // Workspace map (MiB):
    //   [0,8)   a_bf   [8,16)  b_bf     (contiguous: ab indexes)
    //   [16,18) Wa_bf  [18,20) Wb_bf    (contiguous)
    //   [20,28) mem_bf [28,36) memT
    //   [36,52) ta     [52,68) tb       (contiguous; dead after norm_add)
    //   [36,68) e_bf   (reuses ta/tb; unnormalized exp weights, bf16)
    //   [68,76) u_bf
    //   [76,..) rowsum (16 KiB)
    //   [80,97) wm     (4096x1024 f32, unnormalized split-K sums)
    unsigned short* a_bf   = (unsigned short*)(ws + 0 * MB);
    unsigned short* Wa_bf  = (unsigned short*)(ws + 16 * MB);
    unsigned short* mem_bf = (unsigned short*)(ws + 20 * MB);
    unsigned short* memT   = (unsigned short*)(ws + 28 * MB);
    float*          ta     = (float*)(ws + 36 * MB);
    unsigned short* e_bf   = (unsigned short*)(ws + 36 * MB);
    unsigned short* u_bf   = (unsigned short*)(ws + 68 * MB);
    float*          rowsum = (float*)(ws + 76 * MB);
    float*          wm     = (float*)(ws + 80 * MB);

    // 0) zero the atomicAdd accumulators (ws is poisoned 0xAA every call)
    hipMemsetAsync(ta, 0, (size_t)2 * B * H * sizeof(float), stream);   // ta+tb
    hipMemsetAsync(rowsum, 0, (size_t)B * sizeof(float), stream);
    hipMemsetAsync(wm, 0, (size_t)B * H * sizeof(float), stream);

    // 1) converts (a+b merged; Wa+Wb merged)
    cvt2_f32_bf16<<<dim3(B * H / 4 / 256, 2), 256, 0, stream>>>(a, b, a_bf, B * H / 4);
    cvt2_f32_bf16<<<dim3(H * H / 4 / 256, 2), 256, 0, stream>>>(Wa, Wb, Wa_bf, H * H / 4);
    transpose_cvt<<<dim3(H / 32, M / 32), dim3(32, 8), 0, stream>>>(memory, mem_bf, memT, M, H);

    // 2) ta = a@Wa^T + ba ; tb = b@Wb^T + bb
    //    grid.z = 2(ab) x 2(split-K) = 4 -> 1024 blocks = 4/CU
    gemm_bt<1><<<dim3(H / 128, B / 128, 4), 256, 0, stream>>>(
        a_bf, Wa_bf, ta, nullptr, H, H, /*nab=*/2, ba, bb,
        (size_t)B * H, (size_t)H * H, (size_t)B * H, nullptr);

    // 3) u = normalize(ta) + normalize(tb)  (bf16)
    norm_add<<<B, 256, 0, stream>>>(ta, ta + (size_t)B * H, u_bf, H);

    // 4) e = exp(u @ memory^T) bf16 + row sums (1024 blocks = 4/CU already)
    gemm_bt<3><<<dim3(M / 128, B / 128, 1), 256, 0, stream>>>(
        u_bf, mem_bf, nullptr, e_bf, M, H, /*nab=*/1, nullptr, nullptr,
        0, 0, 0, rowsum);

    // 5) wm_raw = e @ memT^T  (split-K x4 -> 1024 blocks = 4/CU, atomicAdd)
    gemm_bt<5><<<dim3(H / 128, B / 128, 4), 256, 0, stream>>>(
        e_bf, memT, wm, nullptr, H, M, /*nab=*/1, nullptr, nullptr,
        0, 0, 0, nullptr);

    // 6) out[b,k,h] = (wm_raw[b,h]/rowsum[b])*Wc[k] + bc[k]
    hub_expand<<<B, 256, 0, stream>>>(wm, rowsum, Wc, bc, out);
}

// Round 13
// 435.304 us; speedup vs baseline: 1.1014x; 1.1014x over previous
//
#include <hip/hip_runtime.h>
#include <stdint.h>

// Problem sizes (fixed by the reference)
#define BSZ 4096
#define HDIM 1024
#define MMEM 4096
#define KOUT 8

typedef __attribute__((ext_vector_type(4))) float f32x4;
typedef __attribute__((ext_vector_type(8))) short s16x8;

__device__ __forceinline__ unsigned short f2bf(float f) {
    uint32_t u = __builtin_bit_cast(uint32_t, f);
    u += 0x7FFFu + ((u >> 16) & 1u);   // round-to-nearest-even
    return (unsigned short)(u >> 16);
}

// ------------- f32 -> bf16 convert, two sources (grid.y selects) -------------
__global__ __launch_bounds__(256) void cvt2_f32_bf16(
    const float* __restrict__ in0, const float* __restrict__ in1,
    unsigned short* __restrict__ out, int n4) {
    int i = blockIdx.x * blockDim.x + threadIdx.x;
    if (i >= n4) return;
    const float* src = blockIdx.y ? in1 : in0;
    float4 v = reinterpret_cast<const float4*>(src)[i];
    ushort4 o;
    o.x = f2bf(v.x); o.y = f2bf(v.y); o.z = f2bf(v.z); o.w = f2bf(v.w);
    reinterpret_cast<ushort4*>(out + (size_t)blockIdx.y * n4 * 4)[i] = o;
}

// ------- memory [M,H] f32 -> mem_bf [M,H] bf16 + memT [H,M] bf16 -------
__global__ __launch_bounds__(256) void transpose_cvt(
    const float* __restrict__ mem, unsigned short* __restrict__ mem_bf,
    unsigned short* __restrict__ memT, int M, int H) {
    __shared__ float tile[32][33];
    const int h0 = blockIdx.x * 32, m0 = blockIdx.y * 32;
    const int tx = threadIdx.x, ty = threadIdx.y;
#pragma unroll
    for (int j = 0; j < 4; ++j) {
        int m = m0 + ty + j * 8;
        float v = mem[(size_t)m * H + h0 + tx];
        tile[ty + j * 8][tx] = v;
        mem_bf[(size_t)m * H + h0 + tx] = f2bf(v);
    }
    __syncthreads();
#pragma unroll
    for (int j = 0; j < 4; ++j) {
        int h = h0 + ty + j * 8;
        memT[(size_t)h * M + m0 + tx] = f2bf(tile[tx][ty + j * 8]);
    }
}

// ---------------- NT bf16 GEMM: C[M,N] = A[M,K] * B[N,K]^T ----------------
// 128x128 tile, BK=32, 4 waves (2x2), 16x16x32 MFMA, fragment-ordered LDS,
// global_load_lds width 16, XCD-bijective block swizzle (requires nwg%8==0).
// 2-phase DOUBLE-BUFFERED staging (T3-minimal): stage tile t+1 while
// computing tile t; counted drain only via vmcnt(0)+raw s_barrier AFTER the
// MFMAs (round-12 profile: __syncthreads-drain exposed ~2060 cy/iter at 12%
// MfmaUtil; occupancy x3 gave only -8% -> pipeline-bound, not TLP-bound).
// grid.z = nab * KSPLIT: ab = z % nab selects input set; ks = z / nab the
// K-chunk (EPI=5 split-K only).
// EPI: 1 = plain f32 store + bias[col]
//      3 = e = exp(acc), store bf16 to Ebf, atomicAdd row sums to rowsum
//      5 = split-K atomicAdd partial (wm; /rowsum deferred to hub_expand)
template <int EPI>
__global__ __launch_bounds__(256, 2) void gemm_bt(
    const unsigned short* __restrict__ A, const unsigned short* __restrict__ Bm,
    float* __restrict__ C, unsigned short* __restrict__ Ebf,
    int N, int Kdim, int nab,
    const float* __restrict__ bias, const float* __restrict__ bias1,
    size_t zA, size_t zB, size_t zC, float* __restrict__ rowsum) {
    __shared__ alignas(16) unsigned short ldsA[8192];  // 2 x 8KB buffers
    __shared__ alignas(16) unsigned short ldsB[8192];

    const int tid  = threadIdx.x;
    const int lane = tid & 63;
    const int w    = tid >> 6;
    const int wm   = w >> 1, wn = w & 1;

    // grid.z decode: input set + K-chunk
    const int z  = blockIdx.z;
    const int ab = z % nab;
    const int ks = z / nab;
    const int KSPLIT = gridDim.z / nab;
    const int Kc = Kdim / KSPLIT;            // this block's K extent
    A  += (size_t)ab * zA + (size_t)ks * Kc;
    Bm += (size_t)ab * zB + (size_t)ks * Kc;
    C  += (size_t)ab * zC;
    const float* bi = (ab != 0 && bias1 != nullptr) ? bias1 : bias;

    // XCD-bijective swizzle
    const int gx  = gridDim.x;
    const int nwg = gx * gridDim.y;          // all launches: nwg % 8 == 0
    const int lid = blockIdx.y * gx + blockIdx.x;
    const int s   = (lid & 7) * (nwg >> 3) + (lid >> 3);
    const int m0 = (s / gx) * 128, n0 = (s % gx) * 128;

    // staging decomposition
    const int g0 = tid >> 6;
    const int ck = (tid >> 4) & 3;
    const int rr = tid & 15;
    size_t baseA0 = (size_t)(m0 + g0 * 16 + rr) * Kdim + ck * 8;
    size_t baseA1 = baseA0 + (size_t)64 * Kdim;
    size_t baseB0 = (size_t)(n0 + g0 * 16 + rr) * Kdim + ck * 8;
    size_t baseB1 = baseB0 + (size_t)64 * Kdim;

    char* ldsAc = (char*)ldsA;
    char* ldsBc = (char*)ldsB;

    auto STAGE = [&](int bufsel, int koff) {
        char* sA = ldsAc + bufsel * 8192;
        char* sB = ldsBc + bufsel * 8192;
        __builtin_amdgcn_global_load_lds(
            (const __attribute__((address_space(1))) void*)(A + baseA0 + koff),
            (__attribute__((address_space(3))) void*)(sA + tid * 16), 16, 0, 0);
        __builtin_amdgcn_global_load_lds(
            (const __attribute__((address_space(1))) void*)(A + baseA1 + koff),
            (__attribute__((address_space(3))) void*)(sA + 4096 + tid * 16), 16, 0, 0);
        __builtin_amdgcn_global_load_lds(
            (const __attribute__((address_space(1))) void*)(Bm + baseB0 + koff),
            (__attribute__((address_space(3))) void*)(sB + tid * 16), 16, 0, 0);
        __builtin_amdgcn_global_load_lds(
            (const __attribute__((address_space(1))) void*)(Bm + baseB1 + koff),
            (__attribute__((address_space(3))) void*)(sB + 4096 + tid * 16), 16, 0, 0);
    };

    f32x4 acc[4][4] = {};
    const int frOff = ((lane >> 4) * 256 + (lane & 15) * 16);  // within 1KB group

    const int nt = Kc >> 5;       // 32-wide K steps
    int cur = 0;

    // prologue: stage tile 0, full drain
    STAGE(0, 0);
    asm volatile("s_waitcnt vmcnt(0)" ::: "memory");
    __builtin_amdgcn_s_barrier();
    __builtin_amdgcn_sched_barrier(0);

    for (int t = 0; t < nt; ++t) {
        // issue next tile's loads into the other buffer (overlaps with
        // this tile's ds_read + MFMA below)
        if (t + 1 < nt) STAGE(cur ^ 1, (t + 1) << 5);

        const char* bA = ldsAc + cur * 8192;
        const char* bB = ldsBc + cur * 8192;
        s16x8 af[4], bfv[4];
#pragma unroll
        for (int m = 0; m < 4; ++m)
            af[m] = *(const s16x8*)(bA + (wm * 4 + m) * 1024 + frOff);
#pragma unroll
        for (int n = 0; n < 4; ++n)
            bfv[n] = *(const s16x8*)(bB + (wn * 4 + n) * 1024 + frOff);
#pragma unroll
        for (int m = 0; m < 4; ++m)
#pragma unroll
            for (int n = 0; n < 4; ++n)
                acc[m][n] = __builtin_amdgcn_mfma_f32_16x16x32_bf16(
                    af[m], bfv[n], acc[m][n], 0, 0, 0);

        // drain the prefetch (overlapped above), then release buffers
        asm volatile("s_waitcnt vmcnt(0)" ::: "memory");
        __builtin_amdgcn_s_barrier();
        __builtin_amdgcn_sched_barrier(0);
        cur ^= 1;
    }

    if (EPI == 1) {
#pragma unroll
        for (int m = 0; m < 4; ++m)
#pragma unroll
            for (int n = 0; n < 4; ++n) {
                int rowb = m0 + wm * 64 + m * 16 + (lane >> 4) * 4;
                int col  = n0 + wn * 64 + n * 16 + (lane & 15);
                float bv = bi[col];
#pragma unroll
                for (int r = 0; r < 4; ++r)
                    C[(size_t)(rowb + r) * N + col] = acc[m][n][r] + bv;
            }
    }

    if (EPI == 3) {
        // exp in place (logits bounded ~|30| << 88: no max subtraction needed)
#pragma unroll
        for (int m = 0; m < 4; ++m)
#pragma unroll
            for (int n = 0; n < 4; ++n)
#pragma unroll
                for (int r = 0; r < 4; ++r)
                    acc[m][n][r] = __expf(acc[m][n][r]);
        // store e as bf16
#pragma unroll
        for (int m = 0; m < 4; ++m)
#pragma unroll
            for (int n = 0; n < 4; ++n) {
                int rowb = m0 + wm * 64 + m * 16 + (lane >> 4) * 4;
                int col  = n0 + wn * 64 + n * 16 + (lane & 15);
#pragma unroll
                for (int r = 0; r < 4; ++r)
                    Ebf[(size_t)(rowb + r) * N + col] = f2bf(acc[m][n][r]);
            }
        // per-row partial sums: butterfly over the 16-lane col group
#pragma unroll
        for (int m = 0; m < 4; ++m)
#pragma unroll
            for (int r = 0; r < 4; ++r) {
                float sv = (acc[m][0][r] + acc[m][1][r]) +
                           (acc[m][2][r] + acc[m][3][r]);
                sv += __shfl_xor(sv, 1);
                sv += __shfl_xor(sv, 2);
                sv += __shfl_xor(sv, 4);
                sv += __shfl_xor(sv, 8);
                if ((lane & 15) == 0) {
                    int row = m0 + wm * 64 + m * 16 + (lane >> 4) * 4 + r;
                    atomicAdd(&rowsum[row], sv);
                }
            }
    }

    if (EPI == 5) {
        // split-K partial accumulate (normalization deferred to hub_expand)
#pragma unroll
        for (int m = 0; m < 4; ++m)
#pragma unroll
            for (int n = 0; n < 4; ++n) {
                int rowb = m0 + wm * 64 + m * 16 + (lane >> 4) * 4;
                int col  = n0 + wn * 64 + n * 16 + (lane & 15);
#pragma unroll
                for (int r = 0; r < 4; ++r)
                    atomicAdd(&C[(size_t)(rowb + r) * N + col], acc[m][n][r]);
            }
    }
}

// -------- u = ta/max(||ta||,eps) + tb/max(||tb||,eps)  (bf16 out) --------
__global__ __launch_bounds__(256) void norm_add(
    const float* __restrict__ ta, const float* __restrict__ tb,
    unsigned short* __restrict__ u, int H) {
    const int row = blockIdx.x;
    const int tid = threadIdx.x;
    float4 va = reinterpret_cast<const float4*>(ta + (size_t)row * H)[tid];
    float4 vb = reinterpret_cast<const float4*>(tb + (size_t)row * H)[tid];
    float sa = va.x * va.x + va.y * va.y + va.z * va.z + va.w * va.w;
    float sb = vb.x * vb.x + vb.y * vb.y + vb.z * vb.z + vb.w * vb.w;
#pragma unroll
    for (int off = 32; off; off >>= 1) {
        sa += __shfl_xor(sa, off);
        sb += __shfl_xor(sb, off);
    }
    __shared__ float reda[4], redb[4];
    if ((tid & 63) == 0) { reda[tid >> 6] = sa; redb[tid >> 6] = sb; }
    __syncthreads();
    float SA = (reda[0] + reda[1]) + (reda[2] + reda[3]);
    float SB = (redb[0] + redb[1]) + (redb[2] + redb[3]);
    float ra = 1.f / fmaxf(sqrtf(SA), 1e-12f);
    float rb = 1.f / fmaxf(sqrtf(SB), 1e-12f);
    ushort4 o;
    o.x = f2bf(va.x * ra + vb.x * rb);
    o.y = f2bf(va.y * ra + vb.y * rb);
    o.z = f2bf(va.z * ra + vb.z * rb);
    o.w = f2bf(va.w * ra + vb.w * rb);
    reinterpret_cast<ushort4*>(u + (size_t)row * H)[tid] = o;
}

// ---- out[b,k,h] = (wm_raw[b,h]/rowsum[b])*Wc[k] + bc[k]  (streaming) ----
__global__ __launch_bounds__(256) void hub_expand(
    const float* __restrict__ wm, const float* __restrict__ rowsum,
    const float* __restrict__ Wc, const float* __restrict__ bc,
    float* __restrict__ out) {
    const int b = blockIdx.x;
    const int t = threadIdx.x;           // 256 threads * float4 = 1024 cols
    float rs = 1.0f / rowsum[b];
    float4 v = reinterpret_cast<const float4*>(wm)[(size_t)b * 256 + t];
    v.x *= rs; v.y *= rs; v.z *= rs; v.w *= rs;
#pragma unroll
    for (int k = 0; k < KOUT; ++k) {
        float wv = Wc[k], bv = bc[k];
        float4 o;
        o.x = v.x * wv + bv; o.y = v.y * wv + bv;
        o.z = v.z * wv + bv; o.w = v.w * wv + bv;
        reinterpret_cast<float4*>(out)[((size_t)b * KOUT + k) * 256 + t] = o;
    }
}

extern "C" void kernel_launch(void* const* d_in, const int* in_sizes, int n_in,
                              void* d_out, int out_size, void* d_ws, size_t ws_size,
                              hipStream_t stream) {
    const float* a      = (const float*)d_in[0];
    const float* b      = (const float*)d_in[1];
    const float* memory = (const float*)d_in[2];
    const float* Wa     = (const float*)d_in[3];
    const float* ba     = (const float*)d_in[4];
    const float* Wb     = (const float*)d_in[5];
    const float* bb     = (const float*)d_in[6];
    const float* Wc     = (const float*)d_in[7];
    const float* bc     = (const float*)d_in[8];
    float* out = (float*)d_out;

    const int B = BSZ, H = HDIM, M = MMEM;
    char* ws = (char*)d_ws;
    const size_t MB = 1u << 20;
    // Workspace map (MiB):
    //   [0,8)   a_bf   [8,16)  b_bf     (contiguous: ab indexes)
    //   [16,18) Wa_bf  [18,20) Wb_bf    (contiguous)
    //   [20,28) mem_bf [28,36) memT
    //   [36,52) ta     [52,68) tb       (contiguous; dead after norm_add)
    //   [36,68) e_bf   (reuses ta/tb; unnormalized exp weights, bf16)
    //   [68,76) u_bf
    //   [76,..) rowsum (16 KiB)
    //   [80,97) wm     (4096x1024 f32, unnormalized split-K sums)
    unsigned short* a_bf   = (unsigned short*)(ws + 0 * MB);
    unsigned short* Wa_bf  = (unsigned short*)(ws + 16 * MB);
    unsigned short* mem_bf = (unsigned short*)(ws + 20 * MB);
    unsigned short* memT   = (unsigned short*)(ws + 28 * MB);
    float*          ta     = (float*)(ws + 36 * MB);
    unsigned short* e_bf   = (unsigned short*)(ws + 36 * MB);
    unsigned short* u_bf   = (unsigned short*)(ws + 68 * MB);
    float*          rowsum = (float*)(ws + 76 * MB);
    float*          wm     = (float*)(ws + 80 * MB);

    // 0) zero the atomicAdd accumulators (ws is poisoned 0xAA every call)
    hipMemsetAsync(rowsum, 0, (size_t)B * sizeof(float), stream);
    hipMemsetAsync(wm, 0, (size_t)B * H * sizeof(float), stream);

    // 1) converts (a+b merged; Wa+Wb merged)
    cvt2_f32_bf16<<<dim3(B * H / 4 / 256, 2), 256, 0, stream>>>(a, b, a_bf, B * H / 4);
    cvt2_f32_bf16<<<dim3(H * H / 4 / 256, 2), 256, 0, stream>>>(Wa, Wb, Wa_bf, H * H / 4);
    transpose_cvt<<<dim3(H / 32, M / 32), dim3(32, 8), 0, stream>>>(memory, mem_bf, memT, M, H);

    // 2) ta = a@Wa^T + ba ; tb = b@Wb^T + bb  (plain store; grid.z = 2 input sets)
    gemm_bt<1><<<dim3(H / 128, B / 128, 2), 256, 0, stream>>>(
        a_bf, Wa_bf, ta, nullptr, H, H, /*nab=*/2, ba, bb,
        (size_t)B * H, (size_t)H * H, (size_t)B * H, nullptr);

    // 3) u = normalize(ta) + normalize(tb)  (bf16)
    norm_add<<<B, 256, 0, stream>>>(ta, ta + (size_t)B * H, u_bf, H);

    // 4) e = exp(u @ memory^T) bf16 + row sums (1024 blocks = 4/CU)
    gemm_bt<3><<<dim3(M / 128, B / 128, 1), 256, 0, stream>>>(
        u_bf, mem_bf, nullptr, e_bf, M, H, /*nab=*/1, nullptr, nullptr,
        0, 0, 0, rowsum);

    // 5) wm_raw = e @ memT^T  (split-K x4 -> 1024 blocks = 4/CU, atomicAdd)
    gemm_bt<5><<<dim3(H / 128, B / 128, 4), 256, 0, stream>>>(
        e_bf, memT, wm, nullptr, H, M, /*nab=*/1, nullptr, nullptr,
        0, 0, 0, nullptr);

    // 6) out[b,k,h] = (wm_raw[b,h]/rowsum[b])*Wc[k] + bc[k]
    hub_expand<<<B, 256, 0, stream>>>(wm, rowsum, Wc, bc, out);
}